// Round 7
// baseline (253.533 us; speedup 1.0000x reference)
//
#include <hip/hip_runtime.h>
#include <hip/hip_bf16.h>

#define B 64
#define S 512
#define H 1024
#define HID 512
#define EPS 1e-5f
#define SCHUNK 16                 // rows per span chunk (fine-grained for balance)
#define NCH (S / SCHUNK)          // 32 chunks
#define KCH 96
#define GEMM_BLOCKS ((HID / 64) * ((3 * H) / KCH))   // 8 * 32 = 256

// ---------------------------------------------------------------------------
// K1: load-balanced span means + pronoun gather -> x (B x 3H), pre-scaled.
// grid (B, 3, NCH), block 256. Thread tx owns channels [tx*4, tx*4+4).
// Each block covers [start,end] ∩ [c*16, c*16+15], accumulates, and
// atomicAdds acc/len into x. x must be pre-zeroed.
// ---------------------------------------------------------------------------
__global__ __launch_bounds__(256) void span_kernel(
    const float* __restrict__ bert, const int* __restrict__ offsets,
    float* __restrict__ x) {
    const int b = blockIdx.x;
    const int e = blockIdx.y;            // 0 = span a, 1 = span b, 2 = pronoun
    const int c = blockIdx.z;            // s-chunk

    int start, end;
    if (e == 0)      { start = offsets[b * 5 + 0]; end = offsets[b * 5 + 1]; }
    else if (e == 1) { start = offsets[b * 5 + 2]; end = offsets[b * 5 + 3]; }
    else             { start = offsets[b * 5 + 4]; end = start; }

    const int lo = max(start, c * SCHUNK);
    const int hi = min(end, c * SCHUNK + SCHUNK - 1);
    if (lo > hi) return;

    const float inv = 1.0f / (float)(end - start + 1);
    const int tx = threadIdx.x;

    float4 acc = make_float4(0.f, 0.f, 0.f, 0.f);
    const float* p = bert + ((size_t)b * S + lo) * H + tx * 4;
#pragma unroll 4
    for (int s = lo; s <= hi; ++s, p += H) {
        const float4 v = *reinterpret_cast<const float4*>(p);
        acc.x += v.x; acc.y += v.y; acc.z += v.z; acc.w += v.w;
    }

    float* xp = x + (size_t)b * (3 * H) + e * H + tx * 4;
    atomicAdd(xp + 0, acc.x * inv);
    atomicAdd(xp + 1, acc.y * inv);
    atomicAdd(xp + 2, acc.z * inv);
    atomicAdd(xp + 3, acc.w * inv);
}

// ---------------------------------------------------------------------------
// K2 (fused): h += x(64x3072) @ W1(3072x512) split-K; the LAST block to
// finish also computes out = leaky(BN(h + b1)) @ W2 + b2.
// grid (8 N-tiles, 32 K-chunks of 96), block 256. h and counter pre-zeroed.
// Release/acquire via __threadfence() around the arrival counter.
// ---------------------------------------------------------------------------
__global__ __launch_bounds__(256) void gemm1_head_kernel(
    const float* __restrict__ x, const float* __restrict__ W1,
    float* __restrict__ h, int* __restrict__ counter,
    const float* __restrict__ b1,
    const float* __restrict__ gamma, const float* __restrict__ beta,
    const float* __restrict__ rm, const float* __restrict__ rv,
    const float* __restrict__ W2, const float* __restrict__ b2,
    float* __restrict__ out) {
    const int t  = threadIdx.x;
    const int jg = t & 15;
    const int mg = t >> 4;
    const int jbase = blockIdx.x * 64 + jg * 4;
    const int kbase = blockIdx.y * KCH;

    float acc[4][4];
#pragma unroll
    for (int i = 0; i < 4; ++i)
#pragma unroll
        for (int j = 0; j < 4; ++j) acc[i][j] = 0.f;

    const int m0 = mg * 4;
    for (int k = kbase; k < kbase + KCH; k += 4) {
        float4 wv[4];
#pragma unroll
        for (int kc = 0; kc < 4; ++kc)
            wv[kc] = *reinterpret_cast<const float4*>(W1 + (size_t)(k + kc) * HID + jbase);
        float4 xv[4];
#pragma unroll
        for (int mi = 0; mi < 4; ++mi)
            xv[mi] = *reinterpret_cast<const float4*>(x + (size_t)(m0 + mi) * (3 * H) + k);
#pragma unroll
        for (int mi = 0; mi < 4; ++mi) {
            acc[mi][0] += xv[mi].x * wv[0].x + xv[mi].y * wv[1].x + xv[mi].z * wv[2].x + xv[mi].w * wv[3].x;
            acc[mi][1] += xv[mi].x * wv[0].y + xv[mi].y * wv[1].y + xv[mi].z * wv[2].y + xv[mi].w * wv[3].y;
            acc[mi][2] += xv[mi].x * wv[0].z + xv[mi].y * wv[1].z + xv[mi].z * wv[2].z + xv[mi].w * wv[3].z;
            acc[mi][3] += xv[mi].x * wv[0].w + xv[mi].y * wv[1].w + xv[mi].z * wv[2].w + xv[mi].w * wv[3].w;
        }
    }

#pragma unroll
    for (int mi = 0; mi < 4; ++mi)
#pragma unroll
        for (int ji = 0; ji < 4; ++ji)
            atomicAdd(&h[(size_t)(m0 + mi) * HID + jbase + ji], acc[mi][ji]);

    // ---- arrival counter: last block does the head ----
    __threadfence();                       // release our h contributions
    __syncthreads();
    __shared__ int lastFlag;
    if (t == 0) {
        const int prev = atomicAdd(counter, 1);
        lastFlag = (prev == GEMM_BLOCKS - 1);
    }
    __syncthreads();
    if (!lastFlag) return;
    __threadfence();                       // acquire everyone's h

    // stage BN scale/shift (512 x 2) and W2 (512 x 3) in LDS
    __shared__ float s_scale[HID];
    __shared__ float s_shift[HID];
    __shared__ float s_w2[HID][3];
#pragma unroll
    for (int r = 0; r < 2; ++r) {
        const int j = t + r * 256;
        const float sc = rsqrtf(rv[j] + EPS) * gamma[j];
        s_scale[j] = sc;
        s_shift[j] = beta[j] + (b1[j] - rm[j]) * sc;
        s_w2[j][0] = W2[j * 3 + 0];
        s_w2[j][1] = W2[j * 3 + 1];
        s_w2[j][2] = W2[j * 3 + 2];
    }
    __syncthreads();

    // thread t: b = t>>2, quarter q = t&3 -> j in [q*128, q*128+128)
    const int b = t >> 2;
    const int q = t & 3;
    float c0 = 0.f, c1 = 0.f, c2 = 0.f;
    const float* hb = h + (size_t)b * HID + q * 128;
    const int j0 = q * 128;
#pragma unroll 8
    for (int jj = 0; jj < 128; ++jj) {
        const int j = j0 + jj;
        float v = hb[jj] * s_scale[j] + s_shift[j];
        v = (v >= 0.f) ? v : 0.01f * v;
        c0 += v * s_w2[j][0];
        c1 += v * s_w2[j][1];
        c2 += v * s_w2[j][2];
    }
    // reduce the 4 quads (consecutive lanes within a wave)
    c0 += __shfl_down(c0, 2); c1 += __shfl_down(c1, 2); c2 += __shfl_down(c2, 2);
    c0 += __shfl_down(c0, 1); c1 += __shfl_down(c1, 1); c2 += __shfl_down(c2, 1);
    if (q == 0) {
        out[b * 3 + 0] = c0 + b2[0];
        out[b * 3 + 1] = c1 + b2[1];
        out[b * 3 + 2] = c2 + b2[2];
    }
}

extern "C" void kernel_launch(void* const* d_in, const int* in_sizes, int n_in,
                              void* d_out, int out_size, void* d_ws, size_t ws_size,
                              hipStream_t stream) {
    const float* bert    = (const float*)d_in[0];
    const int*   offsets = (const int*)d_in[1];
    const float* W1      = (const float*)d_in[2];
    const float* b1      = (const float*)d_in[3];
    const float* gamma   = (const float*)d_in[4];
    const float* beta    = (const float*)d_in[5];
    const float* rm      = (const float*)d_in[6];
    const float* rv      = (const float*)d_in[7];
    const float* W2      = (const float*)d_in[8];
    const float* b2      = (const float*)d_in[9];
    float* out = (float*)d_out;

    float* x       = (float*)d_ws;                                    // B x 3H   = 768 KB
    float* h       = (float*)((char*)d_ws + (size_t)B * 3 * H * 4);   // B x HID  = 128 KB
    int*   counter = (int*)((char*)d_ws + (size_t)(B * 3 * H + B * HID) * 4);

    // zero x, h, and the arrival counter in one contiguous memset
    hipMemsetAsync(d_ws, 0, (size_t)(B * 3 * H + B * HID) * sizeof(float) + 16, stream);

    dim3 g1(B, 3, NCH), t1(256);
    span_kernel<<<g1, t1, 0, stream>>>(bert, offsets, x);

    dim3 g2(HID / 64, (3 * H) / KCH), t2(256);
    gemm1_head_kernel<<<g2, t2, 0, stream>>>(x, W1, h, counter,
                                             b1, gamma, beta, rm, rv, W2, b2, out);
}